// Round 7
// baseline (448.620 us; speedup 1.0000x reference)
//
#include <hip/hip_runtime.h>
#include <math.h>

#define IH 2048
#define IW 2048
#define NBATCH 8
#define TILE 64
#define HALO 3
#define SIW 70           // logical halo tile (TILE + 2*HALO)
#define SI 71            // padded LDS row stride (odd -> conflict-free column reads)
#define ACT_TH 0.1f
#define IMP_TH 0.1f
#define NTILES 8192      // (IW/TILE)*(IH/TILE)*NBATCH

// 1D Gaussian taps, sigma = 7/6, normalized (matches reference 2D outer product).
#define G0 0.0125602013f
#define G1 0.0788279697f
#define G2 0.2372960895f
#define G3 0.3426314790f

__device__ __forceinline__ float fsqrt_f(float x) { return __builtin_amdgcn_sqrtf(x); }
__device__ __forceinline__ float frcp_f(float x)  { return __builtin_amdgcn_rcpf(x); }

// ---------------- Kernel 1: per-batch max --------------------------------
// 256 blocks/batch x 8 batches = 2048 blocks (8/CU). Compile-time stride ->
// 16-iteration unrolled loop, 16 independent loads in flight per thread.
#define MAXBLK 256
#define MAXSTride (MAXBLK * 256)
__global__ __launch_bounds__(256) void batch_max_kernel(
    const float* __restrict__ x, unsigned int* __restrict__ maxbits)
{
    const int b = blockIdx.y;
    const float4* p = (const float4*)(x + (size_t)b * (size_t)(IH * IW));
    float m = 0.0f;
    int i = blockIdx.x * 256 + threadIdx.x;
#pragma unroll
    for (int it = 0; it < (IH * IW / 4) / MAXSTride; ++it, i += MAXSTride) {
        float4 v = p[i];
        m = fmaxf(m, fmaxf(fmaxf(v.x, v.y), fmaxf(v.z, v.w)));
    }
#pragma unroll
    for (int s = 1; s < 64; s <<= 1) m = fmaxf(m, __shfl_xor(m, s));
    __shared__ float sm[4];
    const int lane = threadIdx.x & 63, wv = threadIdx.x >> 6;
    if (lane == 0) sm[wv] = m;
    __syncthreads();
    if (threadIdx.x == 0) {
        m = fmaxf(fmaxf(sm[0], sm[1]), fmaxf(sm[2], sm[3]));
        // x is uniform[0,1): non-negative, so uint-bit compare == float compare
        atomicMax(&maxbits[b], __float_as_uint(m));
    }
}

// ---------------- Kernel 2: fused normalize + block stats ----------------
// One tile per block (32x32x8 grid): HW dispatch staggers block phases so
// memory and compute overlap across the 8 co-resident blocks/CU (the
// persistent variant phase-locked them -> 179us vs 135.6us for this shape).
// Tile body identical to the round-1 135.6us kernel except Phase A uses a
// division-free row-per-wave mapping (same values, same locations).
// Last block to retire (device ticket) computes the final scores.
__global__ __launch_bounds__(256) void piqe_main_kernel(
    const float* __restrict__ x, const unsigned int* __restrict__ maxbits,
    float* __restrict__ contrib_sum, unsigned int* __restrict__ nhsa,
    unsigned int* __restrict__ ticket, float* __restrict__ out)
{
    __shared__ float s_img[SIW * SI];   // 70x70 halo tile, stride 71; n in-place
    __shared__ float s_c;
    __shared__ unsigned int s_a;

    const int tid = threadIdx.x;
    const int b = blockIdx.z;
    const int ox = blockIdx.x * TILE;
    const int oy = blockIdx.y * TILE;
    const float* img0 = x + (size_t)b * (size_t)(IH * IW);
    const float scale = 255.0f / __uint_as_float(maxbits[b]);

    if (tid == 0) { s_c = 0.0f; s_a = 0u; }

    // Phase A: load 70x70 halo tile (edge-clamped), img = round(255*x/max).
    // Wave wv covers rows wv, wv+4, ...; lanes = cols 0..63, lanes 0..5 also
    // cover cols 64..69. No integer division, fully coalesced rows.
    {
        const int lane = tid & 63, wvv = tid >> 6;
        if (ox != 0 && oy != 0 && ox != IW - TILE && oy != IH - TILE) {
            const float* base = img0 + (size_t)(oy - HALO) * IW + (ox - HALO);
            for (int r = wvv; r < SIW; r += 4) {
                const float* rowp = base + (size_t)r * IW;
                float* srow = &s_img[r * SI];
                srow[lane] = rintf(rowp[lane] * scale);
                if (lane < 6) srow[64 + lane] = rintf(rowp[64 + lane] * scale);
            }
        } else {
            for (int r = wvv; r < SIW; r += 4) {
                int gy = oy + r - HALO; gy = max(0, min(IH - 1, gy));
                const float* rowp = img0 + (size_t)gy * IW;
                float* srow = &s_img[r * SI];
                int gx = ox + lane - HALO; gx = max(0, min(IW - 1, gx));
                srow[lane] = rintf(rowp[gx] * scale);
                if (lane < 6) {
                    int gx2 = ox + 64 + lane - HALO; gx2 = max(0, min(IW - 1, gx2));
                    srow[64 + lane] = rintf(rowp[gx2] * scale);
                }
            }
        }
    }
    __syncthreads();

    const float gk[7] = {G0, G1, G2, G3, G2, G1, G0};
    const int cc = tid & 63;          // output column 0..63
    const int gg = tid >> 6;          // row group 0..3
    const int r0 = gg * 16;
    const float* bp = &s_img[r0 * SI + cc];

    // Phase B+C fused: stream 22 halo rows through a 7-deep register ring of
    // horizontal-conv results; emit vertical conv + MSCN per finished row.
    float hm[7], h2[7], pv[4], nv[16];
#pragma unroll
    for (int j = 0; j < 22; ++j) {
        float m = 0.0f, m2 = 0.0f, ctr = 0.0f;
#pragma unroll
        for (int k = 0; k < 7; ++k) {
            float v = bp[j * SI + k];
            if (k == 3) ctr = v;
            m = fmaf(gk[k], v, m);
            m2 = fmaf(gk[k] * v, v, m2);
        }
        hm[j % 7] = m;
        h2[j % 7] = m2;
        if (j >= 3 && j <= 18) pv[(j - 3) & 3] = ctr;
        if (j >= 6) {
            const int r = j - 6;
            float vm = 0.0f, vm2 = 0.0f;
#pragma unroll
            for (int k = 0; k < 7; ++k) {
                vm = fmaf(gk[k], hm[(r + k) % 7], vm);
                vm2 = fmaf(gk[k], h2[(r + k) % 7], vm2);
            }
            float sd = fsqrt_f(fabsf(vm2 - vm * vm));
            nv[r] = (pv[r & 3] - vm) * frcp_f(sd + 1.0f);
        }
    }
    __syncthreads();     // all raw-img reads done -> safe to overwrite in place

    {
        float* wp = &s_img[(r0 + HALO) * SI + (cc + HALO)];
#pragma unroll
        for (int r = 0; r < 16; ++r) wp[r * SI] = nv[r];
    }
    __syncthreads();

    // Phase D: per-16x16-block stats
    const int lane = tid & 63;
    const int wv = tid >> 6;
    const int blk = wv * 4 + (lane >> 4);
    const int L = lane & 15;
    const int bi = blk >> 2, bj = blk & 3;
    const float* np0 = &s_img[(HALO + bi * 16) * SI + (HALO + bj * 16)];

    float rv[16];
    float s1 = 0.0f, s2 = 0.0f;
#pragma unroll
    for (int k = 0; k < 16; ++k) {
        float v = np0[L * SI + k];
        rv[k] = v;
        s1 += v;
        s2 += v * v;
    }
    float c1 = rv[7] + rv[8];
    float c2 = rv[7] * rv[7] + rv[8] * rv[8];
    float u1 = s1 - rv[7] - rv[9];                   // sur: keep col 8, drop 7,9
    float u2 = s2 - rv[7] * rv[7] - rv[9] * rv[9];

    float minstd = __builtin_inff();
    if (L < 4) {
        int offs, stp;
        if (L == 0)      { offs = 0;       stp = 1; }    // top row
        else if (L == 1) { offs = 15 * SI; stp = 1; }    // bottom row
        else if (L == 2) { offs = 0;       stp = SI; }   // left col
        else             { offs = 15;      stp = SI; }   // right col
        float e[16];
#pragma unroll
        for (int k = 0; k < 16; ++k) e[k] = np0[offs + k * stp];
        float w1 = 0.0f, w2 = 0.0f;
#pragma unroll
        for (int k = 0; k < 6; ++k) { w1 += e[k]; w2 += e[k] * e[k]; }
#pragma unroll
        for (int i = 0; i < 11; ++i) {
            float var = (w2 - w1 * w1 * (1.0f / 6.0f)) * (1.0f / 5.0f);
            minstd = fminf(minstd, fsqrt_f(fmaxf(var, 0.0f)));
            if (i < 10) {
                w1 += e[i + 6] - e[i];
                w2 += e[i + 6] * e[i + 6] - e[i] * e[i];
            }
        }
    }

#pragma unroll
    for (int m = 1; m < 16; m <<= 1) {
        s1 += __shfl_xor(s1, m);
        s2 += __shfl_xor(s2, m);
        c1 += __shfl_xor(c1, m);
        c2 += __shfl_xor(c2, m);
        u1 += __shfl_xor(u1, m);
        u2 += __shfl_xor(u2, m);
        minstd = fminf(minstd, __shfl_xor(minstd, m));
    }

    if (L == 0) {
        float bv = fmaxf((s2 - s1 * s1 * (1.0f / 256.0f)) * (1.0f / 255.0f), 0.0f);
        bool active = bv > ACT_TH;
        float cstd = fsqrt_f(fmaxf((c2 - c1 * c1 * (1.0f / 32.0f)) * (1.0f / 31.0f), 0.0f));
        float sstd = fsqrt_f(fmaxf((u2 - u1 * u1 * (1.0f / 224.0f)) * (1.0f / 223.0f), 0.0f));
        float csd = cstd * frcp_f(sstd);         // 0*rcp(0) -> NaN (matches ref 0/0)
        if (csd != csd) csd = 0.0f;              // jnp.where(isnan(csd), 0, csd)
        float sigma = fsqrt_f(bv);
        float beta = fabsf(sigma - csd) * frcp_f(fmaxf(sigma, csd));
        bool wnc = sigma > 2.0f * beta;          // NaN beta -> false (matches)
        bool impaired = minstd < IMP_TH;
        if (active) {
            float contrib = (impaired ? (1.0f - bv) : 0.0f) + (wnc ? bv : 0.0f);
            atomicAdd(&s_c, contrib);
            atomicAdd(&s_a, 1u);
        }
    }
    __syncthreads();
    if (tid == 0) {
        atomicAdd(&contrib_sum[b], s_c);
        atomicAdd(&nhsa[b], s_a);
    }

    // Ticket finish: last retiring block computes the 8 scores (release via
    // ACQ_REL RMW on ticket; all prior blocks' atomics ordered before it).
    __shared__ unsigned int s_win;
    if (tid == 0) {
        unsigned int tk = __hip_atomic_fetch_add(
            ticket, 1u, __ATOMIC_ACQ_REL, __HIP_MEMORY_SCOPE_AGENT);
        s_win = (tk == (unsigned int)(NTILES - 1)) ? 1u : 0u;
    }
    __syncthreads();
    if (s_win && tid < NBATCH) {
        float c = __hip_atomic_load(&contrib_sum[tid], __ATOMIC_RELAXED,
                                    __HIP_MEMORY_SCOPE_AGENT);
        unsigned int a = __hip_atomic_load(&nhsa[tid], __ATOMIC_RELAXED,
                                           __HIP_MEMORY_SCOPE_AGENT);
        out[tid] = (c + 1.0f) / (1.0f + (float)a) * 100.0f;
    }
}

extern "C" void kernel_launch(void* const* d_in, const int* in_sizes, int n_in,
                              void* d_out, int out_size, void* d_ws, size_t ws_size,
                              hipStream_t stream)
{
    const float* x = (const float*)d_in[0];
    float* out = (float*)d_out;

    unsigned int* maxbits = (unsigned int*)d_ws;                    // 8 u32
    float* contrib = (float*)((char*)d_ws + 32);                    // 8 f32
    unsigned int* nhsa = (unsigned int*)((char*)d_ws + 64);         // 8 u32
    unsigned int* ticket = (unsigned int*)((char*)d_ws + 96);       // 1 u32

    hipMemsetAsync(d_ws, 0, 128, stream);
    batch_max_kernel<<<dim3(MAXBLK, NBATCH), 256, 0, stream>>>(x, maxbits);
    piqe_main_kernel<<<dim3(IW / TILE, IH / TILE, NBATCH), 256, 0, stream>>>(
        x, maxbits, contrib, nhsa, ticket, out);
}

// Round 8
// 317.910 us; speedup vs baseline: 1.4112x; 1.4112x over previous
//
#include <hip/hip_runtime.h>
#include <math.h>

#define IH 2048
#define IW 2048
#define NBATCH 8
#define TILE 64
#define HALO 3
#define SIW 70           // logical halo tile (TILE + 2*HALO)
#define SI 72            // LDS row stride; cols 1..70 hold data (col 0,71 pad)
                         // SI%4==0 -> aligned b128 LDS writes of float4 quads
#define ACT_TH 0.1f
#define IMP_TH 0.1f

// 1D Gaussian taps, sigma = 7/6, normalized (matches reference 2D outer product).
#define G0 0.0125602013f
#define G1 0.0788279697f
#define G2 0.2372960895f
#define G3 0.3426314790f

__device__ __forceinline__ float fsqrt_f(float x) { return __builtin_amdgcn_sqrtf(x); }
__device__ __forceinline__ float frcp_f(float x)  { return __builtin_amdgcn_rcpf(x); }

// ---------------- Kernel 1: per-batch max --------------------------------
// 256 blocks/batch x 8 batches = 2048 blocks (8/CU). Compile-time stride ->
// fully unrolled, 16 independent loads in flight per thread.
#define MAXBLK 256
#define MAXSTRIDE (MAXBLK * 256)
__global__ __launch_bounds__(256) void batch_max_kernel(
    const float* __restrict__ x, unsigned int* __restrict__ maxbits)
{
    const int b = blockIdx.y;
    const float4* p = (const float4*)(x + (size_t)b * (size_t)(IH * IW));
    float m = 0.0f;
    int i = blockIdx.x * 256 + threadIdx.x;
#pragma unroll
    for (int it = 0; it < (IH * IW / 4) / MAXSTRIDE; ++it, i += MAXSTRIDE) {
        float4 v = p[i];
        m = fmaxf(m, fmaxf(fmaxf(v.x, v.y), fmaxf(v.z, v.w)));
    }
#pragma unroll
    for (int s = 1; s < 64; s <<= 1) m = fmaxf(m, __shfl_xor(m, s));
    __shared__ float sm[4];
    const int lane = threadIdx.x & 63, wv = threadIdx.x >> 6;
    if (lane == 0) sm[wv] = m;
    __syncthreads();
    if (threadIdx.x == 0) {
        m = fmaxf(fmaxf(sm[0], sm[1]), fmaxf(sm[2], sm[3]));
        // x is uniform[0,1): non-negative, so uint-bit compare == float compare
        atomicMax(&maxbits[b], __float_as_uint(m));
    }
}

// ---------------- Kernel 2: fused normalize + block stats ----------------
// Round-1 tile body (135.6us measured) with a vectorized Phase A:
// interior tiles load 18 aligned float4/row from global (base ox-4) and
// store them as aligned ds_write_b128 (LDS col = global_col-(ox-4), so the
// needed cols ox-3..ox+66 sit at LDS cols 1..70). One tile per block; plain
// atomics only (round 7 proved per-block agent-scope ACQ_REL RMWs shred the
// non-coherent per-XCD L2s: FETCH +9%, latency-bound, 2.2x slower).
__global__ __launch_bounds__(256) void piqe_main_kernel(
    const float* __restrict__ x, const unsigned int* __restrict__ maxbits,
    float* __restrict__ contrib_sum, unsigned int* __restrict__ nhsa)
{
    __shared__ __align__(16) float s_img[SIW * SI];  // 70 rows x 72; n in-place
    __shared__ float s_c;
    __shared__ unsigned int s_a;

    const int tid = threadIdx.x;
    const int b = blockIdx.z;
    const int ox = blockIdx.x * TILE;
    const int oy = blockIdx.y * TILE;
    const float* img0 = x + (size_t)b * (size_t)(IH * IW);
    const float scale = 255.0f / __uint_as_float(maxbits[b]);

    if (tid == 0) { s_c = 0.0f; s_a = 0u; }

    // Phase A: img = round(255*x/max) into LDS cols 1..70 (col0/71 = pad).
    if (ox != 0 && oy != 0 && ox != IW - TILE && oy != IH - TILE) {
        // interior: 70 rows x 18 aligned float4 segments, no clamping
        const float* base4 = img0 + (size_t)(oy - HALO) * IW + (ox - 4);
        for (int u = tid; u < SIW * 18; u += 256) {
            int r = u / 18;                    // const divisor -> magic mul
            int s = u - r * 18;
            float4 q = *(const float4*)(base4 + (size_t)r * IW + 4 * s);
            float4 o;
            o.x = rintf(q.x * scale);
            o.y = rintf(q.y * scale);
            o.z = rintf(q.z * scale);
            o.w = rintf(q.w * scale);
            *(float4*)&s_img[r * SI + 4 * s] = o;   // b128, aligned (SI%4==0)
        }
    } else {
        for (int i = tid; i < SIW * SIW; i += 256) {
            int r = i / SIW, c = i - r * SIW;
            int gy = oy + r - HALO; gy = max(0, min(IH - 1, gy));
            int gx = ox + c - HALO; gx = max(0, min(IW - 1, gx));
            s_img[r * SI + c + 1] = rintf(img0[(size_t)gy * IW + gx] * scale);
        }
    }
    __syncthreads();

    const float gk[7] = {G0, G1, G2, G3, G2, G1, G0};
    const int cc = tid & 63;          // output column 0..63
    const int gg = tid >> 6;          // row group 0..3
    const int r0 = gg * 16;
    const float* bp = &s_img[r0 * SI + cc + 1];     // halo col cc at LDS col cc+1

    // Phase B+C fused: stream 22 halo rows through a 7-deep register ring of
    // horizontal-conv results; emit vertical conv + MSCN per finished row.
    float hm[7], h2[7], pv[4], nv[16];
#pragma unroll
    for (int j = 0; j < 22; ++j) {
        float m = 0.0f, m2 = 0.0f, ctr = 0.0f;
#pragma unroll
        for (int k = 0; k < 7; ++k) {
            float v = bp[j * SI + k];
            if (k == 3) ctr = v;
            m = fmaf(gk[k], v, m);
            m2 = fmaf(gk[k] * v, v, m2);
        }
        hm[j % 7] = m;
        h2[j % 7] = m2;
        if (j >= 3 && j <= 18) pv[(j - 3) & 3] = ctr;
        if (j >= 6) {
            const int r = j - 6;
            float vm = 0.0f, vm2 = 0.0f;
#pragma unroll
            for (int k = 0; k < 7; ++k) {
                vm = fmaf(gk[k], hm[(r + k) % 7], vm);
                vm2 = fmaf(gk[k], h2[(r + k) % 7], vm2);
            }
            float sd = fsqrt_f(fabsf(vm2 - vm * vm));
            nv[r] = (pv[r & 3] - vm) * frcp_f(sd + 1.0f);
        }
    }
    __syncthreads();     // all raw-img reads done -> safe to overwrite in place

    {
        // output col cc -> halo col cc+3 -> LDS col cc+4
        float* wp = &s_img[(r0 + HALO) * SI + cc + HALO + 1];
#pragma unroll
        for (int r = 0; r < 16; ++r) wp[r * SI] = nv[r];
    }
    __syncthreads();

    // Phase D: per-16x16-block stats
    const int lane = tid & 63;
    const int wv = tid >> 6;
    const int blk = wv * 4 + (lane >> 4);
    const int L = lane & 15;
    const int bi = blk >> 2, bj = blk & 3;
    const float* np0 = &s_img[(HALO + bi * 16) * SI + (HALO + 1 + bj * 16)];

    float rv[16];
    {
        // np0 + L*SI is 16B-aligned (base and stride both %4==0) -> 4x b128
        const float4* rp4 = (const float4*)(np0 + L * SI);
        float4 q0 = rp4[0], q1 = rp4[1], q2 = rp4[2], q3 = rp4[3];
        rv[0] = q0.x; rv[1] = q0.y; rv[2]  = q0.z; rv[3]  = q0.w;
        rv[4] = q1.x; rv[5] = q1.y; rv[6]  = q1.z; rv[7]  = q1.w;
        rv[8] = q2.x; rv[9] = q2.y; rv[10] = q2.z; rv[11] = q2.w;
        rv[12] = q3.x; rv[13] = q3.y; rv[14] = q3.z; rv[15] = q3.w;
    }
    float s1 = 0.0f, s2 = 0.0f;
#pragma unroll
    for (int k = 0; k < 16; ++k) {
        float v = rv[k];
        s1 += v;
        s2 += v * v;
    }
    float c1 = rv[7] + rv[8];
    float c2 = rv[7] * rv[7] + rv[8] * rv[8];
    float u1 = s1 - rv[7] - rv[9];                   // sur: keep col 8, drop 7,9
    float u2 = s2 - rv[7] * rv[7] - rv[9] * rv[9];

    float minstd = __builtin_inff();
    if (L < 4) {
        int offs, stp;
        if (L == 0)      { offs = 0;       stp = 1; }    // top row
        else if (L == 1) { offs = 15 * SI; stp = 1; }    // bottom row
        else if (L == 2) { offs = 0;       stp = SI; }   // left col
        else             { offs = 15;      stp = SI; }   // right col
        float e[16];
#pragma unroll
        for (int k = 0; k < 16; ++k) e[k] = np0[offs + k * stp];
        float w1 = 0.0f, w2 = 0.0f;
#pragma unroll
        for (int k = 0; k < 6; ++k) { w1 += e[k]; w2 += e[k] * e[k]; }
#pragma unroll
        for (int i = 0; i < 11; ++i) {
            float var = (w2 - w1 * w1 * (1.0f / 6.0f)) * (1.0f / 5.0f);
            minstd = fminf(minstd, fsqrt_f(fmaxf(var, 0.0f)));
            if (i < 10) {
                w1 += e[i + 6] - e[i];
                w2 += e[i + 6] * e[i + 6] - e[i] * e[i];
            }
        }
    }

#pragma unroll
    for (int m = 1; m < 16; m <<= 1) {
        s1 += __shfl_xor(s1, m);
        s2 += __shfl_xor(s2, m);
        c1 += __shfl_xor(c1, m);
        c2 += __shfl_xor(c2, m);
        u1 += __shfl_xor(u1, m);
        u2 += __shfl_xor(u2, m);
        minstd = fminf(minstd, __shfl_xor(minstd, m));
    }

    if (L == 0) {
        float bv = fmaxf((s2 - s1 * s1 * (1.0f / 256.0f)) * (1.0f / 255.0f), 0.0f);
        bool active = bv > ACT_TH;
        float cstd = fsqrt_f(fmaxf((c2 - c1 * c1 * (1.0f / 32.0f)) * (1.0f / 31.0f), 0.0f));
        float sstd = fsqrt_f(fmaxf((u2 - u1 * u1 * (1.0f / 224.0f)) * (1.0f / 223.0f), 0.0f));
        float csd = cstd * frcp_f(sstd);         // 0*rcp(0) -> NaN (matches ref 0/0)
        if (csd != csd) csd = 0.0f;              // jnp.where(isnan(csd), 0, csd)
        float sigma = fsqrt_f(bv);
        float beta = fabsf(sigma - csd) * frcp_f(fmaxf(sigma, csd));
        bool wnc = sigma > 2.0f * beta;          // NaN beta -> false (matches)
        bool impaired = minstd < IMP_TH;
        if (active) {
            float contrib = (impaired ? (1.0f - bv) : 0.0f) + (wnc ? bv : 0.0f);
            atomicAdd(&s_c, contrib);
            atomicAdd(&s_a, 1u);
        }
    }
    __syncthreads();
    if (tid == 0) {
        atomicAdd(&contrib_sum[b], s_c);
        atomicAdd(&nhsa[b], s_a);
    }
}

// ---------------- Kernel 3: final score ----------------------------------
__global__ void piqe_finish_kernel(const float* __restrict__ contrib_sum,
                                   const unsigned int* __restrict__ nhsa,
                                   float* __restrict__ out)
{
    int b = threadIdx.x;
    if (b < NBATCH)
        out[b] = (contrib_sum[b] + 1.0f) / (1.0f + (float)nhsa[b]) * 100.0f;
}

extern "C" void kernel_launch(void* const* d_in, const int* in_sizes, int n_in,
                              void* d_out, int out_size, void* d_ws, size_t ws_size,
                              hipStream_t stream)
{
    const float* x = (const float*)d_in[0];
    float* out = (float*)d_out;

    unsigned int* maxbits = (unsigned int*)d_ws;                    // 8 u32
    float* contrib = (float*)((char*)d_ws + 32);                    // 8 f32
    unsigned int* nhsa = (unsigned int*)((char*)d_ws + 64);         // 8 u32

    hipMemsetAsync(d_ws, 0, 96, stream);
    batch_max_kernel<<<dim3(MAXBLK, NBATCH), 256, 0, stream>>>(x, maxbits);
    piqe_main_kernel<<<dim3(IW / TILE, IH / TILE, NBATCH), 256, 0, stream>>>(
        x, maxbits, contrib, nhsa);
    piqe_finish_kernel<<<1, 64, 0, stream>>>(contrib, nhsa, out);
}

// Round 9
// 317.669 us; speedup vs baseline: 1.4122x; 1.0008x over previous
//
#include <hip/hip_runtime.h>
#include <math.h>

#define IH 2048
#define IW 2048
#define NBATCH 8
#define TILE 64
#define HALO 3
#define SIW 70           // logical halo tile (TILE + 2*HALO)
#define SI 72            // LDS row stride; cols 1..70 hold data (col 0,71 pad)
                         // SI%4==0 -> aligned b128 LDS writes of float4 quads
#define ACT_TH 0.1f
#define IMP_TH 0.1f

// 1D Gaussian taps, sigma = 7/6, normalized (matches reference 2D outer product).
#define G0 0.0125602013f
#define G1 0.0788279697f
#define G2 0.2372960895f
#define G3 0.3426314790f

__device__ __forceinline__ float fsqrt_f(float x) { return __builtin_amdgcn_sqrtf(x); }
__device__ __forceinline__ float frcp_f(float x)  { return __builtin_amdgcn_rcpf(x); }

// ---------------- Kernel 1: per-batch max --------------------------------
// 256 blocks/batch x 8 batches = 2048 blocks (8/CU). Compile-time stride ->
// fully unrolled, 16 independent loads in flight per thread.
#define MAXBLK 256
#define MAXSTRIDE (MAXBLK * 256)
__global__ __launch_bounds__(256) void batch_max_kernel(
    const float* __restrict__ x, unsigned int* __restrict__ maxbits)
{
    const int b = blockIdx.y;
    const float4* p = (const float4*)(x + (size_t)b * (size_t)(IH * IW));
    float m = 0.0f;
    int i = blockIdx.x * 256 + threadIdx.x;
#pragma unroll
    for (int it = 0; it < (IH * IW / 4) / MAXSTRIDE; ++it, i += MAXSTRIDE) {
        float4 v = p[i];
        m = fmaxf(m, fmaxf(fmaxf(v.x, v.y), fmaxf(v.z, v.w)));
    }
#pragma unroll
    for (int s = 1; s < 64; s <<= 1) m = fmaxf(m, __shfl_xor(m, s));
    __shared__ float sm[4];
    const int lane = threadIdx.x & 63, wv = threadIdx.x >> 6;
    if (lane == 0) sm[wv] = m;
    __syncthreads();
    if (threadIdx.x == 0) {
        m = fmaxf(fmaxf(sm[0], sm[1]), fmaxf(sm[2], sm[3]));
        // x is uniform[0,1): non-negative, so uint-bit compare == float compare
        atomicMax(&maxbits[b], __float_as_uint(m));
    }
}

// ---------------- Kernel 2: fused normalize + block stats ----------------
// Round-8 body with Phase B+C LDS reads forced into ds_read2_b32 pairs:
// the 7-tap window is loaded as 3x 8-byte (align-4) loads + 1 scalar from a
// per-row pointer. Same values, same fma order -> bit-identical output.
// (Single-base scalar reads fit the 16-bit b32 offset field, so the compiler
// never merged them on its own: 154 ds_read_b32/thread was the LDS-pipe
// bottleneck at ~50% of kernel time.)
__global__ __launch_bounds__(256) void piqe_main_kernel(
    const float* __restrict__ x, const unsigned int* __restrict__ maxbits,
    float* __restrict__ contrib_sum, unsigned int* __restrict__ nhsa)
{
    __shared__ __align__(16) float s_img[SIW * SI];  // 70 rows x 72; n in-place
    __shared__ float s_c;
    __shared__ unsigned int s_a;

    const int tid = threadIdx.x;
    const int b = blockIdx.z;
    const int ox = blockIdx.x * TILE;
    const int oy = blockIdx.y * TILE;
    const float* img0 = x + (size_t)b * (size_t)(IH * IW);
    const float scale = 255.0f / __uint_as_float(maxbits[b]);

    if (tid == 0) { s_c = 0.0f; s_a = 0u; }

    // Phase A: img = round(255*x/max) into LDS cols 1..70 (col0/71 = pad).
    if (ox != 0 && oy != 0 && ox != IW - TILE && oy != IH - TILE) {
        // interior: 70 rows x 18 aligned float4 segments, no clamping
        const float* base4 = img0 + (size_t)(oy - HALO) * IW + (ox - 4);
        for (int u = tid; u < SIW * 18; u += 256) {
            int r = u / 18;                    // const divisor -> magic mul
            int s = u - r * 18;
            float4 q = *(const float4*)(base4 + (size_t)r * IW + 4 * s);
            float4 o;
            o.x = rintf(q.x * scale);
            o.y = rintf(q.y * scale);
            o.z = rintf(q.z * scale);
            o.w = rintf(q.w * scale);
            *(float4*)&s_img[r * SI + 4 * s] = o;   // b128, aligned (SI%4==0)
        }
    } else {
        for (int i = tid; i < SIW * SIW; i += 256) {
            int r = i / SIW, c = i - r * SIW;
            int gy = oy + r - HALO; gy = max(0, min(IH - 1, gy));
            int gx = ox + c - HALO; gx = max(0, min(IW - 1, gx));
            s_img[r * SI + c + 1] = rintf(img0[(size_t)gy * IW + gx] * scale);
        }
    }
    __syncthreads();

    const float gk[7] = {G0, G1, G2, G3, G2, G1, G0};
    const int cc = tid & 63;          // output column 0..63
    const int gg = tid >> 6;          // row group 0..3
    const int r0 = gg * 16;
    const float* bp = &s_img[r0 * SI + cc + 1];     // halo col cc at LDS col cc+1

    // Phase B+C fused: stream 22 halo rows through a 7-deep register ring of
    // horizontal-conv results; emit vertical conv + MSCN per finished row.
    float hm[7], h2[7], pv[4], nv[16];
#pragma unroll
    for (int j = 0; j < 22; ++j) {
        const float* p = bp + j * SI;
        float2 q01, q23, q45;
        __builtin_memcpy(&q01, p, 8);       // ds_read2_b32 (align 4)
        __builtin_memcpy(&q23, p + 2, 8);
        __builtin_memcpy(&q45, p + 4, 8);
        float w6 = p[6];
        float w[7] = {q01.x, q01.y, q23.x, q23.y, q45.x, q45.y, w6};
        float m = 0.0f, m2 = 0.0f;
#pragma unroll
        for (int k = 0; k < 7; ++k) {
            float v = w[k];
            m = fmaf(gk[k], v, m);
            m2 = fmaf(gk[k] * v, v, m2);
        }
        hm[j % 7] = m;
        h2[j % 7] = m2;
        if (j >= 3 && j <= 18) pv[(j - 3) & 3] = w[3];
        if (j >= 6) {
            const int r = j - 6;
            float vm = 0.0f, vm2 = 0.0f;
#pragma unroll
            for (int k = 0; k < 7; ++k) {
                vm = fmaf(gk[k], hm[(r + k) % 7], vm);
                vm2 = fmaf(gk[k], h2[(r + k) % 7], vm2);
            }
            float sd = fsqrt_f(fabsf(vm2 - vm * vm));
            nv[r] = (pv[r & 3] - vm) * frcp_f(sd + 1.0f);
        }
    }
    __syncthreads();     // all raw-img reads done -> safe to overwrite in place

    {
        // output col cc -> halo col cc+3 -> LDS col cc+4
        float* wp = &s_img[(r0 + HALO) * SI + cc + HALO + 1];
#pragma unroll
        for (int r = 0; r < 16; ++r) wp[r * SI] = nv[r];
    }
    // NO barrier here: Phase-D wave wv reads only n rows 16*wv..16*wv+15
    // (bi = blk>>2 == wv), which are exactly the rows THIS wave just wrote
    // (gg == wv). Intra-wave LDS ordering is handled by lgkmcnt.

    // Phase D: per-16x16-block stats
    const int lane = tid & 63;
    const int wv = tid >> 6;
    const int blk = wv * 4 + (lane >> 4);
    const int L = lane & 15;
    const int bi = blk >> 2, bj = blk & 3;
    const float* np0 = &s_img[(HALO + bi * 16) * SI + (HALO + 1 + bj * 16)];

    float rv[16];
    {
        // np0 + L*SI is 16B-aligned (base and stride both %4==0) -> 4x b128
        const float4* rp4 = (const float4*)(np0 + L * SI);
        float4 q0 = rp4[0], q1 = rp4[1], q2 = rp4[2], q3 = rp4[3];
        rv[0] = q0.x; rv[1] = q0.y; rv[2]  = q0.z; rv[3]  = q0.w;
        rv[4] = q1.x; rv[5] = q1.y; rv[6]  = q1.z; rv[7]  = q1.w;
        rv[8] = q2.x; rv[9] = q2.y; rv[10] = q2.z; rv[11] = q2.w;
        rv[12] = q3.x; rv[13] = q3.y; rv[14] = q3.z; rv[15] = q3.w;
    }
    float s1 = 0.0f, s2 = 0.0f;
#pragma unroll
    for (int k = 0; k < 16; ++k) {
        float v = rv[k];
        s1 += v;
        s2 += v * v;
    }
    float c1 = rv[7] + rv[8];
    float c2 = rv[7] * rv[7] + rv[8] * rv[8];
    float u1 = s1 - rv[7] - rv[9];                   // sur: keep col 8, drop 7,9
    float u2 = s2 - rv[7] * rv[7] - rv[9] * rv[9];

    float minstd = __builtin_inff();
    if (L < 4) {
        float e[16];
        if (L < 2) {
            // row-direction edges (top row / bottom row): 4 aligned float4
            const float4* ep = (const float4*)(np0 + (L == 0 ? 0 : 15 * SI));
            float4 a0 = ep[0], a1 = ep[1], a2 = ep[2], a3 = ep[3];
            e[0] = a0.x; e[1] = a0.y; e[2]  = a0.z; e[3]  = a0.w;
            e[4] = a1.x; e[5] = a1.y; e[6]  = a1.z; e[7]  = a1.w;
            e[8] = a2.x; e[9] = a2.y; e[10] = a2.z; e[11] = a2.w;
            e[12] = a3.x; e[13] = a3.y; e[14] = a3.z; e[15] = a3.w;
        } else {
            // column-direction edges (left col / right col): stride SI
            const int offs = (L == 2) ? 0 : 15;
#pragma unroll
            for (int k = 0; k < 16; ++k) e[k] = np0[offs + k * SI];
        }
        float w1 = 0.0f, w2 = 0.0f;
#pragma unroll
        for (int k = 0; k < 6; ++k) { w1 += e[k]; w2 += e[k] * e[k]; }
#pragma unroll
        for (int i = 0; i < 11; ++i) {
            float var = (w2 - w1 * w1 * (1.0f / 6.0f)) * (1.0f / 5.0f);
            minstd = fminf(minstd, fsqrt_f(fmaxf(var, 0.0f)));
            if (i < 10) {
                w1 += e[i + 6] - e[i];
                w2 += e[i + 6] * e[i + 6] - e[i] * e[i];
            }
        }
    }

#pragma unroll
    for (int m = 1; m < 16; m <<= 1) {
        s1 += __shfl_xor(s1, m);
        s2 += __shfl_xor(s2, m);
        c1 += __shfl_xor(c1, m);
        c2 += __shfl_xor(c2, m);
        u1 += __shfl_xor(u1, m);
        u2 += __shfl_xor(u2, m);
        minstd = fminf(minstd, __shfl_xor(minstd, m));
    }

    if (L == 0) {
        float bv = fmaxf((s2 - s1 * s1 * (1.0f / 256.0f)) * (1.0f / 255.0f), 0.0f);
        bool active = bv > ACT_TH;
        float cstd = fsqrt_f(fmaxf((c2 - c1 * c1 * (1.0f / 32.0f)) * (1.0f / 31.0f), 0.0f));
        float sstd = fsqrt_f(fmaxf((u2 - u1 * u1 * (1.0f / 224.0f)) * (1.0f / 223.0f), 0.0f));
        float csd = cstd * frcp_f(sstd);         // 0*rcp(0) -> NaN (matches ref 0/0)
        if (csd != csd) csd = 0.0f;              // jnp.where(isnan(csd), 0, csd)
        float sigma = fsqrt_f(bv);
        float beta = fabsf(sigma - csd) * frcp_f(fmaxf(sigma, csd));
        bool wnc = sigma > 2.0f * beta;          // NaN beta -> false (matches)
        bool impaired = minstd < IMP_TH;
        if (active) {
            float contrib = (impaired ? (1.0f - bv) : 0.0f) + (wnc ? bv : 0.0f);
            atomicAdd(&s_c, contrib);
            atomicAdd(&s_a, 1u);
        }
    }
    __syncthreads();
    if (tid == 0) {
        atomicAdd(&contrib_sum[b], s_c);
        atomicAdd(&nhsa[b], s_a);
    }
}

// ---------------- Kernel 3: final score ----------------------------------
__global__ void piqe_finish_kernel(const float* __restrict__ contrib_sum,
                                   const unsigned int* __restrict__ nhsa,
                                   float* __restrict__ out)
{
    int b = threadIdx.x;
    if (b < NBATCH)
        out[b] = (contrib_sum[b] + 1.0f) / (1.0f + (float)nhsa[b]) * 100.0f;
}

extern "C" void kernel_launch(void* const* d_in, const int* in_sizes, int n_in,
                              void* d_out, int out_size, void* d_ws, size_t ws_size,
                              hipStream_t stream)
{
    const float* x = (const float*)d_in[0];
    float* out = (float*)d_out;

    unsigned int* maxbits = (unsigned int*)d_ws;                    // 8 u32
    float* contrib = (float*)((char*)d_ws + 32);                    // 8 f32
    unsigned int* nhsa = (unsigned int*)((char*)d_ws + 64);         // 8 u32

    hipMemsetAsync(d_ws, 0, 96, stream);
    batch_max_kernel<<<dim3(MAXBLK, NBATCH), 256, 0, stream>>>(x, maxbits);
    piqe_main_kernel<<<dim3(IW / TILE, IH / TILE, NBATCH), 256, 0, stream>>>(
        x, maxbits, contrib, nhsa);
    piqe_finish_kernel<<<1, 64, 0, stream>>>(contrib, nhsa, out);
}